// Round 19
// baseline (383.229 us; speedup 1.0000x reference)
//
#include <hip/hip_runtime.h>
#include <hip/hip_fp16.h>
#include <math.h>

#define NN   50000
#define NE   1600000
#define NLBL 200000
#define CAP  80          // max in-degree+1; Poisson(32): P(deg>=80) ~ 1e-12/node
#define NEG  0.2f
#define NBK  196         // ceil(50000/256) dst buckets of 256 nodes
#define CAPB 8800        // bucket capacity: Poisson(8163) + 7 sigma
#define CHK  4096        // edges per bin block
#define GBIN 391         // (NE+CHK-1)/CHK

typedef unsigned short u16;
typedef _Float16 half8 __attribute__((ext_vector_type(8)));
typedef float floatx4 __attribute__((ext_vector_type(4)));

// ---------------- bin phase (device fn): binned counting sort, coalesced writes ----------------
// stage word: [31:24]=bucket, [23:16]=dst&255, [15:0]=src

__device__ void ph_bin(int blk, const int* __restrict__ ei,
                       int* __restrict__ gcnt, unsigned* __restrict__ bins) {
    __shared__ int cntL[NBK];
    __shared__ int offL[NBK];
    __shared__ int curL[NBK];
    __shared__ int curG[NBK];
    __shared__ unsigned stage[CHK];   // 16 KB
    const int tid = threadIdx.x;
    const int e0 = blk * CHK + tid * 16;
    const bool act = (e0 + 15) < NE;

    unsigned pk[16];
    int bb[16];
    if (act) {
#pragma unroll
        for (int g = 0; g < 4; ++g) {
            int4 s4 = *(const int4*)&ei[e0 + g * 4];
            int4 d4 = *(const int4*)&ei[NE + e0 + g * 4];
            int sa[4] = {s4.x, s4.y, s4.z, s4.w};
            int da[4] = {d4.x, d4.y, d4.z, d4.w};
#pragma unroll
            for (int k = 0; k < 4; ++k) {
                int idx = g * 4 + k;
                bb[idx] = da[k] >> 8;
                pk[idx] = (unsigned)sa[k] | ((unsigned)(da[k] & 255) << 16)
                        | ((unsigned)bb[idx] << 24);
            }
        }
    }
    for (int i = tid; i < NBK; i += 256) cntL[i] = 0;
    __syncthreads();
    if (act) {
#pragma unroll
        for (int k = 0; k < 16; ++k) atomicAdd(&cntL[bb[k]], 1);
    }
    __syncthreads();
    if (tid < NBK) {
        int acc = 0;
        for (int i = 0; i < tid; ++i) acc += cntL[i];
        offL[tid] = acc;
        curL[tid] = acc;
    }
    __syncthreads();
    for (int i = tid; i < NBK; i += 256) curG[i] = atomicAdd(&gcnt[i], cntL[i]);
    __syncthreads();
    if (act) {
#pragma unroll
        for (int k = 0; k < 16; ++k) {
            int pos = atomicAdd(&curL[bb[k]], 1);
            stage[pos] = pk[k];
        }
    }
    __syncthreads();
    const int tot = offL[NBK - 1] + cntL[NBK - 1];
    for (int j = tid; j < tot; j += 256) {
        unsigned v = stage[j];
        int b = v >> 24;
        int lr = j - offL[b];
        bins[(size_t)b * CAPB + curG[b] + lr] = v & 0x00FFFFFFu;
    }
}

__global__ __launch_bounds__(256) void k_build(const unsigned* __restrict__ bins,
                                               const int* __restrict__ gcnt,
                                               int* __restrict__ cnt,
                                               u16* __restrict__ csr) {
    __shared__ u16 rows[256 * CAP];   // 40 KB
    __shared__ int cur[256];
    const int b = blockIdx.x, tid = threadIdx.x;
    const int d0 = b << 8;
    const int nd = min(256, NN - d0);
    if (tid < nd) { cur[tid] = 1; rows[tid * CAP] = (u16)(d0 + tid); }  // self-loop slot 0
    __syncthreads();
    const int n = gcnt[b];
    for (int i = tid; i < n; i += 256) {
        unsigned v = bins[(size_t)b * CAPB + i];
        int s = v & 0xFFFF, dl = (v >> 16) & 0xFF;
        int pos = atomicAdd(&cur[dl], 1);
        if (pos < CAP) rows[dl * CAP + pos] = (u16)s;
    }
    __syncthreads();
    const unsigned* rw = (const unsigned*)rows;
    unsigned* cw = (unsigned*)(csr + (size_t)d0 * CAP);
    const int tot = nd * (CAP / 2);
    for (int i = tid; i < tot; i += 256) cw[i] = rw[i];
    if (tid < nd) cnt[d0 + tid] = cur[tid];
}

// ---------------- W -> fp16 fragment layout + gcnt zero ----------------

__global__ __launch_bounds__(256) void k_pre(const float* __restrict__ W1f,
                                             const float* __restrict__ W2f,
                                             const float* __restrict__ W3f,
                                             const float* __restrict__ W4f,
                                             half8* __restrict__ Wf1,
                                             half8* __restrict__ Wf2,
                                             half8* __restrict__ Wf3,
                                             half8* __restrict__ Wf4,
                                             int* __restrict__ gcnt) {
    if (blockIdx.x == 28) {       // folded zero
        int i = threadIdx.x;
        if (i < NBK) gcnt[i] = 0;
        return;
    }
    int e = blockIdx.x * 256 + threadIdx.x;
    const float* W;
    half8* Wf;
    int nout, le;
    if (e < 2048)      { W = W1f; Wf = Wf1; nout = 128; le = e; }
    else if (e < 4096) { W = W2f; Wf = Wf2; nout = 128; le = e - 2048; }
    else if (e < 6144) { W = W3f; Wf = Wf3; nout = 128; le = e - 4096; }
    else               { W = W4f; Wf = Wf4; nout = 64;  le = e - 6144; }
    int c = le >> 8, rem = le & 255, ks = rem >> 6, lane = rem & 63;
    int n = lane & 15, quad = lane >> 4;
    int col = c * 16 + n, k0 = ks * 32 + quad * 8;
    half8 v;
#pragma unroll
    for (int j = 0; j < 8; ++j) v[j] = (_Float16)W[(size_t)(k0 + j) * nout + col];
    Wf[le] = v;
}

// ---------------- layer-1 GEMM tile (fp32 input) fused with bin ----------------
// mfma(argA=W-frag, argB=A-frag): D[row=quad*4+reg -> w_col][col=lane&15 -> a_row].

__device__ __forceinline__ void gemm1_tile(int gt, int lane,
                                           const float* __restrict__ x,
                                           const half8* __restrict__ Wf,
                                           __half* __restrict__ C0,
                                           __half* __restrict__ C1,
                                           const float* __restrict__ a_s,
                                           const float* __restrict__ a_d,
                                           float* __restrict__ asv,
                                           float* __restrict__ adv) {
    const int n = lane & 15, quad = lane >> 4;
    if (gt * 16 >= NN) return;
    const int row = gt * 16 + n;

    half8 a[4];
#pragma unroll
    for (int ks = 0; ks < 4; ++ks) {
        const float* Ap = x + (size_t)row * 128 + ks * 32 + quad * 8;
        float4 f0 = *(const float4*)Ap;
        float4 f1 = *(const float4*)(Ap + 4);
        half8 v;
        v[0] = (_Float16)f0.x; v[1] = (_Float16)f0.y; v[2] = (_Float16)f0.z; v[3] = (_Float16)f0.w;
        v[4] = (_Float16)f1.x; v[5] = (_Float16)f1.y; v[6] = (_Float16)f1.z; v[7] = (_Float16)f1.w;
        a[ks] = v;
    }

    floatx4 acc[8];
#pragma unroll
    for (int c = 0; c < 8; ++c) acc[c] = (floatx4){0.f, 0.f, 0.f, 0.f};
#pragma unroll
    for (int c = 0; c < 8; ++c) {
#pragma unroll
        for (int ks = 0; ks < 4; ++ks) {
            half8 b = Wf[(c * 4 + ks) * 64 + lane];
            acc[c] = __builtin_amdgcn_mfma_f32_16x16x32_f16(b, a[ks], acc[c], 0, 0, 0);
        }
    }

#pragma unroll
    for (int c = 0; c < 8; ++c) {
        __half* Ch = (c < 4) ? C0 : C1;
        int coff = (c < 4) ? c * 16 : (c - 4) * 16;
        __half2 h0 = __floats2half2_rn(acc[c][0], acc[c][1]);
        __half2 h1 = __floats2half2_rn(acc[c][2], acc[c][3]);
        uint2 u;
        __builtin_memcpy(&u.x, &h0, 4);
        __builtin_memcpy(&u.y, &h1, 4);
        *(uint2*)&Ch[(size_t)row * 64 + coff + quad * 4] = u;
    }

    float ps = 0.f, pd = 0.f;
#pragma unroll
    for (int c = 0; c < 8; ++c) {
#pragma unroll
        for (int reg = 0; reg < 4; ++reg) {
            float w = acc[c][reg];
            ps = fmaf(w, a_s[c * 16 + quad * 4 + reg], ps);
            pd = fmaf(w, a_d[c * 16 + quad * 4 + reg], pd);
        }
    }
    ps += __shfl_xor(ps, 16); ps += __shfl_xor(ps, 32);
    pd += __shfl_xor(pd, 16); pd += __shfl_xor(pd, 32);
    if (quad == 0) { asv[row] = ps; adv[row] = pd; }
}

__global__ __launch_bounds__(256) void k_bin_gemm1(const int* __restrict__ ei,
                                                   int* __restrict__ gcnt,
                                                   unsigned* __restrict__ bins,
                                                   const float* __restrict__ x,
                                                   const half8* __restrict__ Wf1,
                                                   __half* __restrict__ G0,
                                                   __half* __restrict__ G1,
                                                   const float* __restrict__ a_s,
                                                   const float* __restrict__ a_d,
                                                   float* __restrict__ asv,
                                                   float* __restrict__ adv) {
    if (blockIdx.x < GBIN) { ph_bin(blockIdx.x, ei, gcnt, bins); return; }
    int gt = (blockIdx.x - GBIN) * 4 + (threadIdx.x >> 6);
    gemm1_tile(gt, threadIdx.x & 63, x, Wf1, G0, G1, a_s, a_d, asv, adv);
}

// fma 8 halves scaled by al into acc[0..7] (v_fma_mix-friendly form)
__device__ __forceinline__ void fma_h8v(half8 h, float al, float* acc) {
#pragma unroll
    for (int k = 0; k < 8; ++k) acc[k] = fmaf(al, (float)h[k], acc[k]);
}

// ---------------- fused GAT layer: aggregation + next-layer GEMM from LDS ----------------
// Block = 16 dsts (4 per wave). Agg rows -> LDS Bs[16][136] (pad 136: b128 reads ~free).
// Then 16x128 @ 128xNOUT2 MFMA tile; writes next gather tables + attn-dot partials.

template <int NOUT2, bool ATTN2>
__global__ __launch_bounds__(256) void k_gat_fused(const __half* __restrict__ h0,
                                                   const __half* __restrict__ h1,
                                                   const int* __restrict__ cnt,
                                                   const u16* __restrict__ csr,
                                                   const float* __restrict__ asv_in,
                                                   const float* __restrict__ adv_in,
                                                   const float* __restrict__ bias,
                                                   const half8* __restrict__ WfN,
                                                   const float* __restrict__ a_sN,
                                                   const float* __restrict__ a_dN,
                                                   float* __restrict__ asvN,
                                                   float* __restrict__ advN,
                                                   __half* __restrict__ GO0,
                                                   __half* __restrict__ GO1) {
    __shared__ float alsL[4][88];
    __shared__ int   srcL[4][88];
    __shared__ _Float16 Bs[16][136];
    __shared__ float psL[16], pdL[16];
    const int lane = threadIdx.x & 63, wv = threadIdx.x >> 6;
    const int d0 = blockIdx.x * 16;
    if (ATTN2 && threadIdx.x < 16) { psL[threadIdx.x] = 0.f; pdL[threadIdx.x] = 0.f; }

    // ---- aggregation: 4 dsts per wave ----
    for (int it = 0; it < 4; ++it) {
        const int d = d0 + wv * 4 + it;      // 3125*16 = 50000: always < NN
        int deg = cnt[d]; if (deg > CAP) deg = CAP;
        const float advd = adv_in[d];
        const u16* rowp = csr + (size_t)d * CAP;

        int j0 = lane, j1 = lane + 64;
        int s0 = 0, s1 = 0;
        float e0 = -INFINITY, e1 = -INFINITY;
        if (j0 < deg) {
            s0 = rowp[j0];
            float t = asv_in[s0] + advd;
            e0 = (t >= 0.f) ? t : NEG * t;
        }
        if (j1 < deg) {
            s1 = rowp[j1];
            float t = asv_in[s1] + advd;
            e1 = (t >= 0.f) ? t : NEG * t;
        }
        float m = fmaxf(e0, e1);
#pragma unroll
        for (int off = 32; off; off >>= 1) m = fmaxf(m, __shfl_xor(m, off));
        float p0 = (j0 < deg) ? __expf(e0 - m) : 0.f;
        float p1 = (j1 < deg) ? __expf(e1 - m) : 0.f;
        float s = p0 + p1;
#pragma unroll
        for (int off = 32; off; off >>= 1) s += __shfl_xor(s, off);
        float inv = 1.f / s;
        alsL[wv][j0] = p0 * inv;
        srcL[wv][j0] = s0;
        if (j1 < 88) { alsL[wv][j1] = p1 * inv; srcL[wv][j1] = s1; }

        int slot = lane >> 3, r = lane & 7;
        int degp = (deg + 7) & ~7;
#pragma unroll
        for (int half = 0; half < 2; ++half) {
            const __half* ht = half ? h1 : h0;
            float acc[8];
#pragma unroll
            for (int k = 0; k < 8; ++k) acc[k] = 0.f;
            for (int base = 0; base < degp; base += 8) {
                int idx = base + slot;
                float al = alsL[wv][idx];
                int   sj = srcL[wv][idx];
                half8 hv = *(const half8*)&ht[(size_t)sj * 64 + r * 8];
                fma_h8v(hv, al, acc);
            }
#pragma unroll
            for (int k = 0; k < 8; ++k) {
                acc[k] += __shfl_xor(acc[k], 8);
                acc[k] += __shfl_xor(acc[k], 16);
                acc[k] += __shfl_xor(acc[k], 32);
            }
            if (slot == 0) {   // relu(+bias) -> fp16 row in LDS
                _Float16* bp = &Bs[wv * 4 + it][half * 64 + r * 8];
#pragma unroll
                for (int k = 0; k < 8; ++k)
                    bp[k] = (_Float16)fmaxf(acc[k] + bias[half * 64 + r * 8 + k], 0.f);
            }
        }
    }
    __syncthreads();

    // ---- fused next-layer GEMM: 16 rows (LDS) x WfN -> GO tables ----
    constexpr int CTW = (NOUT2 == 128) ? 2 : 1;   // c-tiles per wave
    const int n = lane & 15, quad = lane >> 4;
    const int row = d0 + n;
    float ps = 0.f, pd = 0.f;
#pragma unroll
    for (int ct = 0; ct < CTW; ++ct) {
        const int c = wv * CTW + ct;
        floatx4 acc2 = (floatx4){0.f, 0.f, 0.f, 0.f};
#pragma unroll
        for (int ks = 0; ks < 4; ++ks) {
            half8 b = *(const half8*)&Bs[n][ks * 32 + quad * 8];
            half8 a = WfN[(c * 4 + ks) * 64 + lane];
            acc2 = __builtin_amdgcn_mfma_f32_16x16x32_f16(a, b, acc2, 0, 0, 0);
        }
        __half* Ch = (NOUT2 == 64 || c < 4) ? GO0 : GO1;
        int coff = (NOUT2 == 64 || c < 4) ? c * 16 : (c - 4) * 16;
        __half2 h0p = __floats2half2_rn(acc2[0], acc2[1]);
        __half2 h1p = __floats2half2_rn(acc2[2], acc2[3]);
        uint2 u;
        __builtin_memcpy(&u.x, &h0p, 4);
        __builtin_memcpy(&u.y, &h1p, 4);
        *(uint2*)&Ch[(size_t)row * 64 + coff + quad * 4] = u;
        if (ATTN2) {
#pragma unroll
            for (int reg = 0; reg < 4; ++reg) {
                float w = acc2[reg];
                ps = fmaf(w, a_sN[c * 16 + quad * 4 + reg], ps);
                pd = fmaf(w, a_dN[c * 16 + quad * 4 + reg], pd);
            }
        }
    }
    if (ATTN2) {
        ps += __shfl_xor(ps, 16); ps += __shfl_xor(ps, 32);
        pd += __shfl_xor(pd, 16); pd += __shfl_xor(pd, 32);
        if (quad == 0) { atomicAdd(&psL[n], ps); atomicAdd(&pdL[n], pd); }
        __syncthreads();
        if (threadIdx.x < 16) {
            asvN[d0 + threadIdx.x] = psL[threadIdx.x];
            advN[d0 + threadIdx.x] = pdL[threadIdx.x];
        }
    }
}

// ---------------- GCN aggregation (64-col table, 128B rows) ----------------

__global__ __launch_bounds__(256) void k_gcn_agg(const __half* __restrict__ h,
                                                 const int* __restrict__ cnt,
                                                 const u16* __restrict__ csr,
                                                 const float* __restrict__ bias,
                                                 __half* __restrict__ z) {
    __shared__ float nmL[4][88];
    __shared__ int   srcL[4][88];
    int lane = threadIdx.x & 63, wv = threadIdx.x >> 6;
    int d = blockIdx.x * 4 + wv;
    if (d >= NN) return;
    int degc = cnt[d];
    int deg = degc > CAP ? CAP : degc;
    float did = rsqrtf((float)degc);
    const u16* rowp = csr + (size_t)d * CAP;

    int j0 = lane, j1 = lane + 64;
    int s0 = 0, s1 = 0;
    float n0 = 0.f, n1 = 0.f;
    if (j0 < deg) { s0 = rowp[j0]; n0 = rsqrtf((float)cnt[s0]) * did; }
    if (j1 < deg) { s1 = rowp[j1]; n1 = rsqrtf((float)cnt[s1]) * did; }
    nmL[wv][j0] = n0;
    srcL[wv][j0] = s0;
    if (j1 < 88) { nmL[wv][j1] = n1; srcL[wv][j1] = s1; }

    int slot = lane >> 3, r = lane & 7;
    float acc[8];
#pragma unroll
    for (int k = 0; k < 8; ++k) acc[k] = 0.f;

    int degp = (deg + 7) & ~7;
    for (int base = 0; base < degp; base += 8) {
        int idx = base + slot;
        float nm = nmL[wv][idx];
        int   sj = srcL[wv][idx];
        half8 hv = *(const half8*)&h[(size_t)sj * 64 + r * 8];
        fma_h8v(hv, nm, acc);
    }
#pragma unroll
    for (int k = 0; k < 8; ++k) {
        acc[k] += __shfl_xor(acc[k], 8);
        acc[k] += __shfl_xor(acc[k], 16);
        acc[k] += __shfl_xor(acc[k], 32);
    }
    if (slot == 0) {
        __half2 ho[4];
#pragma unroll
        for (int k = 0; k < 4; ++k) {
            float oa = acc[2 * k]     + bias[r * 8 + 2 * k];
            float ob = acc[2 * k + 1] + bias[r * 8 + 2 * k + 1];
            ho[k] = __floats2half2_rn(oa, ob);
        }
        uint4 u;
        __builtin_memcpy(&u, &ho[0], 16);
        *(uint4*)&z[(size_t)d * 64 + r * 8] = u;   // decode reuses z soon: keep in L2
    }
}

// ---------------- link decode (fp16 z, fp32 dot) ----------------

__global__ __launch_bounds__(256) void k_decode(const __half* __restrict__ z,
                                                const int* __restrict__ eli,
                                                float* __restrict__ outp) {
    int lane = threadIdx.x & 63, wv = threadIdx.x >> 6;
    int g = lane >> 4, r = lane & 15;
    int idx = (blockIdx.x * 4 + wv) * 4 + g;
    if (idx >= NLBL) return;
    int a = eli[idx], b = eli[NLBL + idx];
    uint2 ua = *(const uint2*)&z[(size_t)a * 64 + r * 4];
    uint2 ub = *(const uint2*)&z[(size_t)b * 64 + r * 4];
    float2 a0 = __half22float2(*(__half2*)&ua.x);
    float2 a1 = __half22float2(*(__half2*)&ua.y);
    float2 b0 = __half22float2(*(__half2*)&ub.x);
    float2 b1 = __half22float2(*(__half2*)&ub.y);
    float v = a0.x * b0.x + a0.y * b0.y + a1.x * b1.x + a1.y * b1.y;
#pragma unroll
    for (int off = 8; off; off >>= 1) v += __shfl_xor(v, off);
    if (r == 0) outp[idx] = v;
}

// ---------------- launch ----------------

extern "C" void kernel_launch(void* const* d_in, const int* in_sizes, int n_in,
                              void* d_out, int out_size, void* d_ws, size_t ws_size,
                              hipStream_t stream) {
    const float* x   = (const float*)d_in[0];
    const int*   ei  = (const int*)d_in[1];
    const int*   eli = (const int*)d_in[2];
    const float* W1 = (const float*)d_in[3];
    const float* a1s = (const float*)d_in[4];
    const float* a1d = (const float*)d_in[5];
    const float* b1 = (const float*)d_in[6];
    const float* W2 = (const float*)d_in[7];
    const float* a2s = (const float*)d_in[8];
    const float* a2d = (const float*)d_in[9];
    const float* b2 = (const float*)d_in[10];
    const float* W3 = (const float*)d_in[11];
    const float* a3s = (const float*)d_in[12];
    const float* a3d = (const float*)d_in[13];
    const float* b3 = (const float*)d_in[14];
    const float* W4 = (const float*)d_in[15];
    const float* b4 = (const float*)d_in[16];
    float* outp = (float*)d_out;

    char* p = (char*)d_ws;
    auto alloc = [&](size_t bytes) -> char* {
        char* r = p;
        p += (bytes + 255) & ~(size_t)255;
        return r;
    };
    int*    cnt  = (int*)alloc((size_t)NN * 4);
    u16*    csr  = (u16*)alloc((size_t)NN * CAP * 2);
    int*    gcnt = (int*)alloc((size_t)NBK * 4);
    float*  asvA = (float*)alloc((size_t)NN * 4);
    float*  advA = (float*)alloc((size_t)NN * 4);
    float*  asvB = (float*)alloc((size_t)NN * 4);
    float*  advB = (float*)alloc((size_t)NN * 4);
    __half* G0   = (__half*)alloc((size_t)NN * 64 * 2);    // gather table halves (ping)
    __half* G1   = (__half*)alloc((size_t)NN * 64 * 2);
    __half* H0   = (__half*)alloc((size_t)NN * 64 * 2);    // gather table halves (pong)
    __half* H1   = (__half*)alloc((size_t)NN * 64 * 2);
    __half* Z0   = (__half*)alloc((size_t)NN * 64 * 2);    // gcn input table
    __half* zf   = (__half*)alloc((size_t)NN * 64 * 2);    // gcn output
    half8*  Wf1  = (half8*)alloc(2048 * 16);
    half8*  Wf2  = (half8*)alloc(2048 * 16);
    half8*  Wf3  = (half8*)alloc(2048 * 16);
    half8*  Wf4  = (half8*)alloc(1024 * 16);
    unsigned* bins = (unsigned*)alloc((size_t)NBK * CAPB * 4);

    const int gG1   = GBIN + 782;          // bin blocks + gemm1 blocks
    const int gFus  = NN / 16;             // 3125 blocks, 16 dsts each
    const int gNode = (NN + 3) / 4;
    const int gDec  = (NLBL + 15) / 16;

    k_pre<<<29, 256, 0, stream>>>(W1, W2, W3, W4, Wf1, Wf2, Wf3, Wf4, gcnt);
    k_bin_gemm1<<<gG1, 256, 0, stream>>>(ei, gcnt, bins, x, Wf1, G0, G1, a1s, a1d, asvA, advA);
    k_build<<<NBK, 256, 0, stream>>>(bins, gcnt, cnt, csr);

    // GAT layer 1 agg + GEMM2 fused
    k_gat_fused<128, true><<<gFus, 256, 0, stream>>>(G0, G1, cnt, csr, asvA, advA, b1,
                                                     Wf2, a2s, a2d, asvB, advB, H0, H1);
    // GAT layer 2 agg + GEMM3 fused
    k_gat_fused<128, true><<<gFus, 256, 0, stream>>>(H0, H1, cnt, csr, asvB, advB, b2,
                                                     Wf3, a3s, a3d, asvA, advA, G0, G1);
    // GAT layer 3 agg + GEMM4 fused (64-col output, no attn)
    k_gat_fused<64, false><<<gFus, 256, 0, stream>>>(G0, G1, cnt, csr, asvA, advA, b3,
                                                     Wf4, nullptr, nullptr, nullptr, nullptr,
                                                     Z0, Z0);
    k_gcn_agg<<<gNode, 256, 0, stream>>>(Z0, cnt, csr, b4, zf);
    k_decode<<<gDec, 256, 0, stream>>>(zf, eli, outp);
}

// Round 20
// 370.730 us; speedup vs baseline: 1.0337x; 1.0337x over previous
//
#include <hip/hip_runtime.h>
#include <hip/hip_fp16.h>
#include <math.h>

#define NN   50000
#define NE   1600000
#define NLBL 200000
#define CAP  80          // max in-degree+1; Poisson(32): P(deg>=80) ~ 1e-12/node
#define NEG  0.2f
#define NBK  196         // ceil(50000/256) dst buckets of 256 nodes
#define CAPB 8800        // bucket capacity: Poisson(8163) + 7 sigma
#define CHK  4096        // edges per bin block
#define GBIN 391         // (NE+CHK-1)/CHK

typedef unsigned short u16;
typedef _Float16 half8 __attribute__((ext_vector_type(8)));
typedef float floatx4 __attribute__((ext_vector_type(4)));

// ---------------- bin phase (device fn): binned counting sort, coalesced writes ----------------
// stage word: [31:24]=bucket, [23:16]=dst&255, [15:0]=src

__device__ void ph_bin(int blk, const int* __restrict__ ei,
                       int* __restrict__ gcnt, unsigned* __restrict__ bins) {
    __shared__ int cntL[NBK];
    __shared__ int offL[NBK];
    __shared__ int curL[NBK];
    __shared__ int curG[NBK];
    __shared__ unsigned stage[CHK];   // 16 KB
    const int tid = threadIdx.x;
    const int e0 = blk * CHK + tid * 16;
    const bool act = (e0 + 15) < NE;

    unsigned pk[16];
    int bb[16];
    if (act) {
#pragma unroll
        for (int g = 0; g < 4; ++g) {
            int4 s4 = *(const int4*)&ei[e0 + g * 4];
            int4 d4 = *(const int4*)&ei[NE + e0 + g * 4];
            int sa[4] = {s4.x, s4.y, s4.z, s4.w};
            int da[4] = {d4.x, d4.y, d4.z, d4.w};
#pragma unroll
            for (int k = 0; k < 4; ++k) {
                int idx = g * 4 + k;
                bb[idx] = da[k] >> 8;
                pk[idx] = (unsigned)sa[k] | ((unsigned)(da[k] & 255) << 16)
                        | ((unsigned)bb[idx] << 24);
            }
        }
    }
    for (int i = tid; i < NBK; i += 256) cntL[i] = 0;
    __syncthreads();
    if (act) {
#pragma unroll
        for (int k = 0; k < 16; ++k) atomicAdd(&cntL[bb[k]], 1);
    }
    __syncthreads();
    if (tid < NBK) {
        int acc = 0;
        for (int i = 0; i < tid; ++i) acc += cntL[i];
        offL[tid] = acc;
        curL[tid] = acc;
    }
    __syncthreads();
    for (int i = tid; i < NBK; i += 256) curG[i] = atomicAdd(&gcnt[i], cntL[i]);
    __syncthreads();
    if (act) {
#pragma unroll
        for (int k = 0; k < 16; ++k) {
            int pos = atomicAdd(&curL[bb[k]], 1);
            stage[pos] = pk[k];
        }
    }
    __syncthreads();
    const int tot = offL[NBK - 1] + cntL[NBK - 1];
    for (int j = tid; j < tot; j += 256) {
        unsigned v = stage[j];
        int b = v >> 24;
        int lr = j - offL[b];
        bins[(size_t)b * CAPB + curG[b] + lr] = v & 0x00FFFFFFu;
    }
}

__global__ __launch_bounds__(256) void k_build(const unsigned* __restrict__ bins,
                                               const int* __restrict__ gcnt,
                                               int* __restrict__ cnt,
                                               u16* __restrict__ csr) {
    __shared__ u16 rows[256 * CAP];   // 40 KB
    __shared__ int cur[256];
    const int b = blockIdx.x, tid = threadIdx.x;
    const int d0 = b << 8;
    const int nd = min(256, NN - d0);
    if (tid < nd) { cur[tid] = 1; rows[tid * CAP] = (u16)(d0 + tid); }  // self-loop slot 0
    __syncthreads();
    const int n = gcnt[b];
    for (int i = tid; i < n; i += 256) {
        unsigned v = bins[(size_t)b * CAPB + i];
        int s = v & 0xFFFF, dl = (v >> 16) & 0xFF;
        int pos = atomicAdd(&cur[dl], 1);
        if (pos < CAP) rows[dl * CAP + pos] = (u16)s;
    }
    __syncthreads();
    const unsigned* rw = (const unsigned*)rows;
    unsigned* cw = (unsigned*)(csr + (size_t)d0 * CAP);
    const int tot = nd * (CAP / 2);
    for (int i = tid; i < tot; i += 256) cw[i] = rw[i];
    if (tid < nd) cnt[d0 + tid] = cur[tid];
}

// ---------------- W -> fp16 fragment layout + gcnt zero ----------------

__global__ __launch_bounds__(256) void k_pre(const float* __restrict__ W1f,
                                             const float* __restrict__ W2f,
                                             const float* __restrict__ W3f,
                                             const float* __restrict__ W4f,
                                             half8* __restrict__ Wf1,
                                             half8* __restrict__ Wf2,
                                             half8* __restrict__ Wf3,
                                             half8* __restrict__ Wf4,
                                             int* __restrict__ gcnt) {
    if (blockIdx.x == 28) {       // folded zero
        int i = threadIdx.x;
        if (i < NBK) gcnt[i] = 0;
        return;
    }
    int e = blockIdx.x * 256 + threadIdx.x;
    const float* W;
    half8* Wf;
    int nout, le;
    if (e < 2048)      { W = W1f; Wf = Wf1; nout = 128; le = e; }
    else if (e < 4096) { W = W2f; Wf = Wf2; nout = 128; le = e - 2048; }
    else if (e < 6144) { W = W3f; Wf = Wf3; nout = 128; le = e - 4096; }
    else               { W = W4f; Wf = Wf4; nout = 64;  le = e - 6144; }
    int c = le >> 8, rem = le & 255, ks = rem >> 6, lane = rem & 63;
    int n = lane & 15, quad = lane >> 4;
    int col = c * 16 + n, k0 = ks * 32 + quad * 8;
    half8 v;
#pragma unroll
    for (int j = 0; j < 8; ++j) v[j] = (_Float16)W[(size_t)(k0 + j) * nout + col];
    Wf[le] = v;
}

// ---------------- MFMA fp16 GEMM tile (device fn): 16 rows per call ----------------
// mfma(argA=W-frag, argB=A-frag): D[row=quad*4+reg -> w_col][col=lane&15 -> a_row].
// NOUT=128: cols 0-63 -> C0, 64-127 -> C1 (split 128B rows). NOUT=64: C0 only.

template <int NOUT, bool ATTN, typename TA>
__device__ __forceinline__ void gemm_tile(int gt, int lane,
                                          const TA* __restrict__ A0,
                                          const TA* __restrict__ A1,
                                          const half8* __restrict__ Wf,
                                          __half* __restrict__ C0,
                                          __half* __restrict__ C1,
                                          const float* __restrict__ a_s,
                                          const float* __restrict__ a_d,
                                          float* __restrict__ asv,
                                          float* __restrict__ adv) {
    constexpr int CT = NOUT / 16;
    const int n = lane & 15, quad = lane >> 4;
    if (gt * 16 >= NN) return;            // 3125 tiles cover 50000 rows exactly
    const int row = gt * 16 + n;

    half8 a[4];
#pragma unroll
    for (int ks = 0; ks < 4; ++ks) {
        int c128 = ks * 32 + quad * 8;
        if constexpr (sizeof(TA) == 2) {
            const TA* Ah = (c128 < 64) ? A0 : A1;
            a[ks] = *(const half8*)((const _Float16*)Ah + (size_t)row * 64 + (c128 & 63));
        } else {
            const float* Ap = (const float*)A0 + (size_t)row * 128 + c128;
            float4 f0 = *(const float4*)Ap;
            float4 f1 = *(const float4*)(Ap + 4);
            half8 v;
            v[0] = (_Float16)f0.x; v[1] = (_Float16)f0.y; v[2] = (_Float16)f0.z; v[3] = (_Float16)f0.w;
            v[4] = (_Float16)f1.x; v[5] = (_Float16)f1.y; v[6] = (_Float16)f1.z; v[7] = (_Float16)f1.w;
            a[ks] = v;
        }
    }

    floatx4 acc[CT];
#pragma unroll
    for (int c = 0; c < CT; ++c) acc[c] = (floatx4){0.f, 0.f, 0.f, 0.f};
#pragma unroll
    for (int c = 0; c < CT; ++c) {
#pragma unroll
        for (int ks = 0; ks < 4; ++ks) {
            half8 b = Wf[(c * 4 + ks) * 64 + lane];
            acc[c] = __builtin_amdgcn_mfma_f32_16x16x32_f16(b, a[ks], acc[c], 0, 0, 0);
        }
    }

#pragma unroll
    for (int c = 0; c < CT; ++c) {
        __half* Ch = (NOUT == 64 || c < 4) ? C0 : C1;
        int coff = (NOUT == 64 || c < 4) ? c * 16 : (c - 4) * 16;
        __half2 h0 = __floats2half2_rn(acc[c][0], acc[c][1]);
        __half2 h1 = __floats2half2_rn(acc[c][2], acc[c][3]);
        uint2 u;
        __builtin_memcpy(&u.x, &h0, 4);
        __builtin_memcpy(&u.y, &h1, 4);
        *(uint2*)&Ch[(size_t)row * 64 + coff + quad * 4] = u;
    }

    if (ATTN) {   // fused attn dots (fp32 from acc); reduce across quads
        float ps = 0.f, pd = 0.f;
#pragma unroll
        for (int c = 0; c < CT; ++c) {
#pragma unroll
            for (int reg = 0; reg < 4; ++reg) {
                float w = acc[c][reg];
                ps = fmaf(w, a_s[c * 16 + quad * 4 + reg], ps);
                pd = fmaf(w, a_d[c * 16 + quad * 4 + reg], pd);
            }
        }
        ps += __shfl_xor(ps, 16); ps += __shfl_xor(ps, 32);
        pd += __shfl_xor(pd, 16); pd += __shfl_xor(pd, 32);
        if (quad == 0) { asv[row] = ps; adv[row] = pd; }
    }
}

// fused: blocks [0,GBIN) bin edges; blocks [GBIN, GBIN+782) run layer-1 GEMM.
__global__ __launch_bounds__(256) void k_bin_gemm1(const int* __restrict__ ei,
                                                   int* __restrict__ gcnt,
                                                   unsigned* __restrict__ bins,
                                                   const float* __restrict__ x,
                                                   const half8* __restrict__ Wf1,
                                                   __half* __restrict__ G0,
                                                   __half* __restrict__ G1,
                                                   const float* __restrict__ a_s,
                                                   const float* __restrict__ a_d,
                                                   float* __restrict__ asv,
                                                   float* __restrict__ adv) {
    if (blockIdx.x < GBIN) { ph_bin(blockIdx.x, ei, gcnt, bins); return; }
    int gt = (blockIdx.x - GBIN) * 4 + (threadIdx.x >> 6);
    gemm_tile<128, true, float>(gt, threadIdx.x & 63, x, x, Wf1, G0, G1, a_s, a_d, asv, adv);
}

// standalone 64-thread GEMM kernels: 3125 one-wave blocks for load balance
template <int NOUT, bool ATTN>
__global__ __launch_bounds__(64) void k_gemm64(const __half* __restrict__ A0,
                                               const __half* __restrict__ A1,
                                               const half8* __restrict__ Wf,
                                               __half* __restrict__ C0,
                                               __half* __restrict__ C1,
                                               const float* __restrict__ a_s,
                                               const float* __restrict__ a_d,
                                               float* __restrict__ asv,
                                               float* __restrict__ adv) {
    gemm_tile<NOUT, ATTN, __half>(blockIdx.x, threadIdx.x & 63, A0, A1, Wf, C0, C1,
                                  a_s, a_d, asv, adv);
}

// fma 8 halves scaled by al into acc[0..7] (v_fma_mix-friendly form)
__device__ __forceinline__ void fma_h8v(half8 h, float al, float* acc) {
#pragma unroll
    for (int k = 0; k < 8; ++k) acc[k] = fmaf(al, (float)h[k], acc[k]);
}

// ---------------- GAT aggregation: 2 compact 6.4MB passes (128B rows) ----------------

__global__ __launch_bounds__(256) void k_gat_agg(const __half* __restrict__ h0,
                                                 const __half* __restrict__ h1,
                                                 const int* __restrict__ cnt,
                                                 const u16* __restrict__ csr,
                                                 const float* __restrict__ asv,
                                                 const float* __restrict__ adv,
                                                 const float* __restrict__ bias,
                                                 __half* __restrict__ out0,
                                                 __half* __restrict__ out1) {
    __shared__ float alsL[4][88];
    __shared__ int   srcL[4][88];
    int lane = threadIdx.x & 63, wv = threadIdx.x >> 6;
    int d = blockIdx.x * 4 + wv;
    if (d >= NN) return;
    int deg = cnt[d]; if (deg > CAP) deg = CAP;
    const float advd = adv[d];
    const u16* rowp = csr + (size_t)d * CAP;

    // ---- phase A: exact softmax over <=80 edges in 2 register chunks ----
    int j0 = lane, j1 = lane + 64;
    int s0 = 0, s1 = 0;
    float e0 = -INFINITY, e1 = -INFINITY;
    if (j0 < deg) {
        s0 = rowp[j0];
        float t = asv[s0] + advd;
        e0 = (t >= 0.f) ? t : NEG * t;
    }
    if (j1 < deg) {
        s1 = rowp[j1];
        float t = asv[s1] + advd;
        e1 = (t >= 0.f) ? t : NEG * t;
    }
    float m = fmaxf(e0, e1);
#pragma unroll
    for (int off = 32; off; off >>= 1) m = fmaxf(m, __shfl_xor(m, off));
    float p0 = (j0 < deg) ? __expf(e0 - m) : 0.f;
    float p1 = (j1 < deg) ? __expf(e1 - m) : 0.f;
    float s = p0 + p1;
#pragma unroll
    for (int off = 32; off; off >>= 1) s += __shfl_xor(s, off);
    float inv = 1.f / s;
    alsL[wv][j0] = p0 * inv;
    srcL[wv][j0] = s0;
    if (j1 < 88) { alsL[wv][j1] = p1 * inv; srcL[wv][j1] = s1; }

    // ---- phase B: two passes; 8 edge-slots x 8 lanes x 8 cols ----
    int slot = lane >> 3, r = lane & 7;
    int degp = (deg + 7) & ~7;
#pragma unroll
    for (int half = 0; half < 2; ++half) {
        const __half* ht = half ? h1 : h0;
        __half* ot = half ? out1 : out0;
        float acc[8];
#pragma unroll
        for (int k = 0; k < 8; ++k) acc[k] = 0.f;

        for (int base = 0; base < degp; base += 8) {
            int idx = base + slot;
            float al = alsL[wv][idx];
            int   sj = srcL[wv][idx];
            half8 hv = *(const half8*)&ht[(size_t)sj * 64 + r * 8];
            fma_h8v(hv, al, acc);
        }
#pragma unroll
        for (int k = 0; k < 8; ++k) {
            acc[k] += __shfl_xor(acc[k], 8);
            acc[k] += __shfl_xor(acc[k], 16);
            acc[k] += __shfl_xor(acc[k], 32);
        }
        if (slot == 0) {
            __half2 ho[4];
#pragma unroll
            for (int k = 0; k < 4; ++k) {
                float oa = fmaxf(acc[2 * k]     + bias[half * 64 + r * 8 + 2 * k],     0.f);
                float ob = fmaxf(acc[2 * k + 1] + bias[half * 64 + r * 8 + 2 * k + 1], 0.f);
                ho[k] = __floats2half2_rn(oa, ob);
            }
            uint4 u;
            __builtin_memcpy(&u, &ho[0], 16);
            *(uint4*)&ot[(size_t)d * 64 + r * 8] = u;   // plain store: next GEMM reads from L2
        }
    }
}

// ---------------- GCN aggregation (64-col table, 128B rows) ----------------

__global__ __launch_bounds__(256) void k_gcn_agg(const __half* __restrict__ h,
                                                 const int* __restrict__ cnt,
                                                 const u16* __restrict__ csr,
                                                 const float* __restrict__ bias,
                                                 __half* __restrict__ z) {
    __shared__ float nmL[4][88];
    __shared__ int   srcL[4][88];
    int lane = threadIdx.x & 63, wv = threadIdx.x >> 6;
    int d = blockIdx.x * 4 + wv;
    if (d >= NN) return;
    int degc = cnt[d];
    int deg = degc > CAP ? CAP : degc;
    float did = rsqrtf((float)degc);
    const u16* rowp = csr + (size_t)d * CAP;

    int j0 = lane, j1 = lane + 64;
    int s0 = 0, s1 = 0;
    float n0 = 0.f, n1 = 0.f;
    if (j0 < deg) { s0 = rowp[j0]; n0 = rsqrtf((float)cnt[s0]) * did; }
    if (j1 < deg) { s1 = rowp[j1]; n1 = rsqrtf((float)cnt[s1]) * did; }
    nmL[wv][j0] = n0;
    srcL[wv][j0] = s0;
    if (j1 < 88) { nmL[wv][j1] = n1; srcL[wv][j1] = s1; }

    int slot = lane >> 3, r = lane & 7;
    float acc[8];
#pragma unroll
    for (int k = 0; k < 8; ++k) acc[k] = 0.f;

    int degp = (deg + 7) & ~7;
    for (int base = 0; base < degp; base += 8) {
        int idx = base + slot;
        float nm = nmL[wv][idx];
        int   sj = srcL[wv][idx];
        half8 hv = *(const half8*)&h[(size_t)sj * 64 + r * 8];
        fma_h8v(hv, nm, acc);
    }
#pragma unroll
    for (int k = 0; k < 8; ++k) {
        acc[k] += __shfl_xor(acc[k], 8);
        acc[k] += __shfl_xor(acc[k], 16);
        acc[k] += __shfl_xor(acc[k], 32);
    }
    if (slot == 0) {
        __half2 ho[4];
#pragma unroll
        for (int k = 0; k < 4; ++k) {
            float oa = acc[2 * k]     + bias[r * 8 + 2 * k];
            float ob = acc[2 * k + 1] + bias[r * 8 + 2 * k + 1];
            ho[k] = __floats2half2_rn(oa, ob);
        }
        uint4 u;
        __builtin_memcpy(&u, &ho[0], 16);
        *(uint4*)&z[(size_t)d * 64 + r * 8] = u;   // decode reuses z soon: keep in L2
    }
}

// ---------------- link decode (fp16 z, fp32 dot) ----------------

__global__ __launch_bounds__(256) void k_decode(const __half* __restrict__ z,
                                                const int* __restrict__ eli,
                                                float* __restrict__ outp) {
    int lane = threadIdx.x & 63, wv = threadIdx.x >> 6;
    int g = lane >> 4, r = lane & 15;
    int idx = (blockIdx.x * 4 + wv) * 4 + g;
    if (idx >= NLBL) return;
    int a = eli[idx], b = eli[NLBL + idx];
    uint2 ua = *(const uint2*)&z[(size_t)a * 64 + r * 4];
    uint2 ub = *(const uint2*)&z[(size_t)b * 64 + r * 4];
    float2 a0 = __half22float2(*(__half2*)&ua.x);
    float2 a1 = __half22float2(*(__half2*)&ua.y);
    float2 b0 = __half22float2(*(__half2*)&ub.x);
    float2 b1 = __half22float2(*(__half2*)&ub.y);
    float v = a0.x * b0.x + a0.y * b0.y + a1.x * b1.x + a1.y * b1.y;
#pragma unroll
    for (int off = 8; off; off >>= 1) v += __shfl_xor(v, off);
    if (r == 0) outp[idx] = v;
}

// ---------------- launch ----------------

extern "C" void kernel_launch(void* const* d_in, const int* in_sizes, int n_in,
                              void* d_out, int out_size, void* d_ws, size_t ws_size,
                              hipStream_t stream) {
    const float* x   = (const float*)d_in[0];
    const int*   ei  = (const int*)d_in[1];
    const int*   eli = (const int*)d_in[2];
    const float* W1 = (const float*)d_in[3];
    const float* a1s = (const float*)d_in[4];
    const float* a1d = (const float*)d_in[5];
    const float* b1 = (const float*)d_in[6];
    const float* W2 = (const float*)d_in[7];
    const float* a2s = (const float*)d_in[8];
    const float* a2d = (const float*)d_in[9];
    const float* b2 = (const float*)d_in[10];
    const float* W3 = (const float*)d_in[11];
    const float* a3s = (const float*)d_in[12];
    const float* a3d = (const float*)d_in[13];
    const float* b3 = (const float*)d_in[14];
    const float* W4 = (const float*)d_in[15];
    const float* b4 = (const float*)d_in[16];
    float* outp = (float*)d_out;

    char* p = (char*)d_ws;
    auto alloc = [&](size_t bytes) -> char* {
        char* r = p;
        p += (bytes + 255) & ~(size_t)255;
        return r;
    };
    int*    cnt  = (int*)alloc((size_t)NN * 4);
    u16*    csr  = (u16*)alloc((size_t)NN * CAP * 2);
    int*    gcnt = (int*)alloc((size_t)NBK * 4);
    float*  asv  = (float*)alloc((size_t)NN * 4);
    float*  advv = (float*)alloc((size_t)NN * 4);
    __half* G0   = (__half*)alloc((size_t)NN * 64 * 2);    // gather table halves
    __half* G1   = (__half*)alloc((size_t)NN * 64 * 2);
    __half* B1a  = (__half*)alloc((size_t)NN * 64 * 2);    // layer outputs (split)
    __half* B1b  = (__half*)alloc((size_t)NN * 64 * 2);
    __half* B2a  = (__half*)alloc((size_t)NN * 64 * 2);
    __half* B2b  = (__half*)alloc((size_t)NN * 64 * 2);
    __half* zf   = (__half*)alloc((size_t)NN * 64 * 2);    // gcn output
    half8*  Wf1  = (half8*)alloc(2048 * 16);
    half8*  Wf2  = (half8*)alloc(2048 * 16);
    half8*  Wf3  = (half8*)alloc(2048 * 16);
    half8*  Wf4  = (half8*)alloc(1024 * 16);
    unsigned* bins = (unsigned*)alloc((size_t)NBK * CAPB * 4);

    const int gG1   = GBIN + 782;          // bin blocks + gemm1 blocks
    const int gGemm = (NN + 15) / 16;      // 3125 one-wave blocks
    const int gNode = (NN + 3) / 4;
    const int gDec  = (NLBL + 15) / 16;

    k_pre<<<29, 256, 0, stream>>>(W1, W2, W3, W4, Wf1, Wf2, Wf3, Wf4, gcnt);
    k_bin_gemm1<<<gG1, 256, 0, stream>>>(ei, gcnt, bins, x, Wf1, G0, G1, a1s, a1d, asv, advv);
    k_build<<<NBK, 256, 0, stream>>>(bins, gcnt, cnt, csr);

    k_gat_agg<<<gNode, 256, 0, stream>>>(G0, G1, cnt, csr, asv, advv, b1, B1a, B1b);

    k_gemm64<128, true><<<gGemm, 64, 0, stream>>>(B1a, B1b, Wf2, G0, G1, a2s, a2d, asv, advv);
    k_gat_agg<<<gNode, 256, 0, stream>>>(G0, G1, cnt, csr, asv, advv, b2, B2a, B2b);

    k_gemm64<128, true><<<gGemm, 64, 0, stream>>>(B2a, B2b, Wf3, G0, G1, a3s, a3d, asv, advv);
    k_gat_agg<<<gNode, 256, 0, stream>>>(G0, G1, cnt, csr, asv, advv, b3, B1a, B1b);

    k_gemm64<64, false><<<gGemm, 64, 0, stream>>>(B1a, B1b, Wf4, G0, G0, nullptr, nullptr, nullptr, nullptr);
    k_gcn_agg<<<gNode, 256, 0, stream>>>(G0, cnt, csr, b4, zf);

    k_decode<<<gDec, 256, 0, stream>>>(zf, eli, outp);
}